// Round 2
// baseline (694.146 us; speedup 1.0000x reference)
//
#include <hip/hip_runtime.h>
#include <cstdint>
#include <cstddef>

// FiBiNET fused inference, fp32 baseline.
// B=16384, F=26, D=16, P=325 pairs, hidden 64->32->1.
// Algebra: se_p[b,p,:] = A[b,i]*A[b,j] * p[b,p,:]  (se = e * A), so the
// second bilinear is a per-pair scalar rescale of the first. We compute
// u = (e_i @ W_p) ⊙ e_j once and accumulate y1 += u@w1a[p] + (c*u)@w1b[p].

#define F 26
#define D 16
#define P_PAIRS 325
#define BATCH 16384
#define RPB 64
#define NBLK (BATCH / RPB)      // 256
#define BN_EPS 1e-3f

struct PairTab { unsigned char iu[P_PAIRS]; unsigned char ju[P_PAIRS]; };
static constexpr PairTab make_pairs() {
    PairTab t{};
    int p = 0;
    for (int a = 0; a < F; ++a)
        for (int b = a + 1; b < F; ++b) { t.iu[p] = (unsigned char)a; t.ju[p] = (unsigned char)b; ++p; }
    return t;
}
__constant__ PairTab PT = make_pairs();

__device__ __forceinline__ void fma4(float s, const float4& wv, float4& acc) {
    acc.x = fmaf(s, wv.x, acc.x);
    acc.y = fmaf(s, wv.y, acc.y);
    acc.z = fmaf(s, wv.z, acc.z);
    acc.w = fmaf(s, wv.w, acc.w);
}

// ---------------- K3: repack w1 [10400,64] -> w1cat [325][32][64] ----------------
// k<16 -> w1 row p*16+k (u path), k>=16 -> w1 row 5200+p*16+(k-16) (c*u path)
__global__ __launch_bounds__(256) void k_w1cat(const float* __restrict__ w1,
                                               float* __restrict__ w1cat) {
    int idx = blockIdx.x * 256 + threadIdx.x;
    if (idx >= P_PAIRS * 32 * 64) return;
    int o   = idx & 63;
    int rem = idx >> 6;          // p*32 + k
    int k   = rem & 31;
    int p   = rem >> 5;
    int row = (k < 16) ? (p * 16 + k) : (5200 + p * 16 + (k - 16));
    w1cat[idx] = w1[row * 64 + o];
}

// ---------------- K1: gather embeddings, SE attention ----------------
__global__ __launch_bounds__(256) void k_prep(const int* __restrict__ x,
        const float* __restrict__ emb, const float* __restrict__ sw1,
        const float* __restrict__ sw2, float* __restrict__ e_ws,
        float* __restrict__ a_ws) {
    __shared__ float z_s[RPB][F];
    __shared__ float sw1_s[F * 13];
    __shared__ float sw2_s[13 * F];
    const int tid = threadIdx.x;
    const int b0 = blockIdx.x * RPB;
    for (int i = tid; i < F * 13; i += 256) { sw1_s[i] = sw1[i]; sw2_s[i] = sw2[i]; }
    for (int idx = tid; idx < RPB * F; idx += 256) {
        int r = idx / F;
        int f = idx - r * F;
        int b = b0 + r;
        int id = x[b * F + f] + f * 1000;
        const float4* src = (const float4*)(emb + (size_t)id * D);
        float4 v0 = src[0], v1 = src[1], v2 = src[2], v3 = src[3];
        float4* dst = (float4*)(e_ws + ((size_t)b * F + f) * D);
        dst[0] = v0; dst[1] = v1; dst[2] = v2; dst[3] = v3;
        float s = v0.x + v0.y + v0.z + v0.w + v1.x + v1.y + v1.z + v1.w
                + v2.x + v2.y + v2.z + v2.w + v3.x + v3.y + v3.z + v3.w;
        z_s[r][f] = s * (1.0f / 16.0f);
    }
    __syncthreads();
    if (tid < RPB) {
        int b = b0 + tid;
        float s1[13];
        #pragma unroll
        for (int o = 0; o < 13; ++o) {
            float acc = 0.f;
            #pragma unroll
            for (int f = 0; f < F; ++f) acc = fmaf(z_s[tid][f], sw1_s[f * 13 + o], acc);
            s1[o] = fmaxf(acc, 0.0f);
        }
        #pragma unroll
        for (int f = 0; f < F; ++f) {
            float acc = 0.f;
            #pragma unroll
            for (int o = 0; o < 13; ++o) acc = fmaf(s1[o], sw2_s[o * F + f], acc);
            a_ws[(size_t)b * F + f] = fmaxf(acc, 0.0f);
        }
    }
}

// ---------------- K2: fused bilinear + big GEMM (partial y1) ----------------
// grid 512: blockIdx = mtile(256) + 256*pairhalf(2). Block owns 64 batch rows.
// Threads 256. Per pair: phase1 builds uvT[32][rows] in LDS (u rows 0..15,
// v=c*u rows 16..31), phase2 rank-16-per-khalf update of y[64r x 64o].
// Weight tiles (w1cat 8KB + W_p 1KB) double-buffered in LDS, prefetched
// into registers one pair ahead.
__global__ __launch_bounds__(256) void k_main(
        const float* __restrict__ e_ws, const float* __restrict__ a_ws,
        const float* __restrict__ w1cat, const float* __restrict__ blw,
        float* __restrict__ ypart) {
    __shared__ __align__(16) float smem[4096 + 32 * 80 + 512];
    float* stage = smem;                    // [2][2048] w1cat double buffer
    float* uvT   = smem + 4096;             // [32][80]  (pad 64->80 rows stride)
    float* wp    = smem + 4096 + 32 * 80;   // [2][256]  W_p double buffer

    const int tid   = threadIdx.x;
    const int mtile = blockIdx.x & (NBLK - 1);
    const int ph    = blockIdx.x >> 8;      // pair-half 0/1
    const int b0    = mtile * RPB;
    const int p_beg = ph ? 163 : 0;
    const int p_end = ph ? P_PAIRS : 163;

    // phase-1 mapping: thread = (row r1, 4-wide dout slice q1)
    const int r1 = tid >> 2;
    const int q1 = (tid & 3) << 2;
    // phase-2 mapping: thread = (khalf, row-group of 8, 4-wide out slice)
    const int khalf = tid >> 7;
    const int r0    = ((tid >> 4) & 7) << 3;
    const int o0    = (tid & 15) << 2;

    float4 acc[8];
    #pragma unroll
    for (int i = 0; i < 8; ++i) acc[i] = make_float4(0.f, 0.f, 0.f, 0.f);

    { // stage first pair's weights
        const float4* src = (const float4*)(w1cat + (size_t)p_beg * 2048) + tid * 2;
        float4 a = src[0], b = src[1];
        float4* dst = (float4*)stage + tid * 2;
        dst[0] = a; dst[1] = b;
        if (tid < 64) ((float4*)wp)[tid] = ((const float4*)(blw + (size_t)p_beg * 256))[tid];
    }
    __syncthreads();

    for (int p = p_beg; p < p_end; ++p) {
        const int buf  = (p - p_beg) & 1;
        const int nbuf = buf ^ 1;
        float4 pf0, pf1, pfw;
        const bool more = (p + 1 < p_end);
        if (more) {
            const float4* src = (const float4*)(w1cat + (size_t)(p + 1) * 2048) + tid * 2;
            pf0 = src[0]; pf1 = src[1];
            if (tid < 64) pfw = ((const float4*)(blw + (size_t)(p + 1) * 256))[tid];
        }

        // ---- phase 1: t = e_i @ W_p ; u = t.*e_j ; v = c*u ; transpose to LDS
        const int iu = PT.iu[p], ju = PT.ju[p];
        const float* ei = e_ws + ((size_t)(b0 + r1) * F + iu) * D;
        const float* ej = e_ws + ((size_t)(b0 + r1) * F + ju) * D;
        float4 ea = ((const float4*)ei)[0];
        float4 eb = ((const float4*)ei)[1];
        float4 ec = ((const float4*)ei)[2];
        float4 ed = ((const float4*)ei)[3];
        const float* wpb = wp + buf * 256;
        float4 t4 = make_float4(0.f, 0.f, 0.f, 0.f);
        {
            float4 wv;
            wv = *(const float4*)(wpb + 0  * D + q1); fma4(ea.x, wv, t4);
            wv = *(const float4*)(wpb + 1  * D + q1); fma4(ea.y, wv, t4);
            wv = *(const float4*)(wpb + 2  * D + q1); fma4(ea.z, wv, t4);
            wv = *(const float4*)(wpb + 3  * D + q1); fma4(ea.w, wv, t4);
            wv = *(const float4*)(wpb + 4  * D + q1); fma4(eb.x, wv, t4);
            wv = *(const float4*)(wpb + 5  * D + q1); fma4(eb.y, wv, t4);
            wv = *(const float4*)(wpb + 6  * D + q1); fma4(eb.z, wv, t4);
            wv = *(const float4*)(wpb + 7  * D + q1); fma4(eb.w, wv, t4);
            wv = *(const float4*)(wpb + 8  * D + q1); fma4(ec.x, wv, t4);
            wv = *(const float4*)(wpb + 9  * D + q1); fma4(ec.y, wv, t4);
            wv = *(const float4*)(wpb + 10 * D + q1); fma4(ec.z, wv, t4);
            wv = *(const float4*)(wpb + 11 * D + q1); fma4(ec.w, wv, t4);
            wv = *(const float4*)(wpb + 12 * D + q1); fma4(ed.x, wv, t4);
            wv = *(const float4*)(wpb + 13 * D + q1); fma4(ed.y, wv, t4);
            wv = *(const float4*)(wpb + 14 * D + q1); fma4(ed.z, wv, t4);
            wv = *(const float4*)(wpb + 15 * D + q1); fma4(ed.w, wv, t4);
        }
        float4 ej4 = *(const float4*)(ej + q1);
        float ai = a_ws[(size_t)(b0 + r1) * F + iu];
        float aj = a_ws[(size_t)(b0 + r1) * F + ju];
        float c  = ai * aj;
        float4 u4 = make_float4(t4.x * ej4.x, t4.y * ej4.y, t4.z * ej4.z, t4.w * ej4.w);
        float4 v4 = make_float4(u4.x * c, u4.y * c, u4.z * c, u4.w * c);
        uvT[(q1 + 0) * 80 + r1] = u4.x;
        uvT[(q1 + 1) * 80 + r1] = u4.y;
        uvT[(q1 + 2) * 80 + r1] = u4.z;
        uvT[(q1 + 3) * 80 + r1] = u4.w;
        uvT[(q1 + 16) * 80 + r1] = v4.x;
        uvT[(q1 + 17) * 80 + r1] = v4.y;
        uvT[(q1 + 18) * 80 + r1] = v4.z;
        uvT[(q1 + 19) * 80 + r1] = v4.w;
        __syncthreads();

        // ---- phase 2: y[r0..r0+7][o0..o0+3] += sum_k uvT[k][r] * w1cat[k][o]
        const float* wc  = stage + buf * 2048 + (khalf << 4) * 64;
        const float* uvb = uvT + (khalf << 4) * 80;
        #pragma unroll
        for (int kk = 0; kk < 16; ++kk) {
            float4 w4 = *(const float4*)(wc + kk * 64 + o0);
            float4 ua = *(const float4*)(uvb + kk * 80 + r0);
            float4 ub = *(const float4*)(uvb + kk * 80 + r0 + 4);
            fma4(ua.x, w4, acc[0]); fma4(ua.y, w4, acc[1]);
            fma4(ua.z, w4, acc[2]); fma4(ua.w, w4, acc[3]);
            fma4(ub.x, w4, acc[4]); fma4(ub.y, w4, acc[5]);
            fma4(ub.z, w4, acc[6]); fma4(ub.w, w4, acc[7]);
        }
        if (more) {
            float4* dst = (float4*)(stage + nbuf * 2048) + tid * 2;
            dst[0] = pf0; dst[1] = pf1;
            if (tid < 64) ((float4*)(wp + nbuf * 256))[tid] = pfw;
        }
        __syncthreads();
    }

    float* yp = ypart + ((size_t)(ph * 2 + khalf) * BATCH + b0) * 64;
    #pragma unroll
    for (int ri = 0; ri < 8; ++ri)
        *(float4*)(yp + (r0 + ri) * 64 + o0) = acc[ri];
}

// ---------------- K4: merge partials + BN/ReLU MLP tail ----------------
__global__ __launch_bounds__(256) void k_epi(
        const float* __restrict__ ypart,
        const float* __restrict__ b1, const float* __restrict__ g1,
        const float* __restrict__ be1, const float* __restrict__ m1,
        const float* __restrict__ v1,
        const float* __restrict__ w2, const float* __restrict__ b2,
        const float* __restrict__ g2, const float* __restrict__ be2,
        const float* __restrict__ m2, const float* __restrict__ v2,
        const float* __restrict__ w3, const float* __restrict__ b3,
        float* __restrict__ out) {
    __shared__ __align__(16) float h1s[RPB * 64];
    __shared__ float h2s[RPB * 36];
    const int tid = threadIdx.x;
    const int b0 = blockIdx.x * RPB;
    const int rr = tid >> 2;
    const int cc = (tid & 3) << 4;
    size_t base = ((size_t)b0 + rr) * 64 + cc;

    float4 s[4];
    #pragma unroll
    for (int q = 0; q < 4; ++q) s[q] = *(const float4*)(ypart + base + q * 4);
    #pragma unroll
    for (int part = 1; part < 4; ++part) {
        const float* src = ypart + (size_t)part * BATCH * 64 + base;
        #pragma unroll
        for (int q = 0; q < 4; ++q) {
            float4 t = *(const float4*)(src + q * 4);
            s[q].x += t.x; s[q].y += t.y; s[q].z += t.z; s[q].w += t.w;
        }
    }
    #pragma unroll
    for (int q = 0; q < 4; ++q) {
        int o = cc + q * 4;
        float4 g  = *(const float4*)(g1 + o);
        float4 vv = *(const float4*)(v1 + o);
        float4 mm = *(const float4*)(m1 + o);
        float4 bb = *(const float4*)(be1 + o);
        float4 bi = *(const float4*)(b1 + o);
        float4 h;
        h.x = fmaxf(g.x * (s[q].x + bi.x - mm.x) * rsqrtf(vv.x + BN_EPS) + bb.x, 0.f);
        h.y = fmaxf(g.y * (s[q].y + bi.y - mm.y) * rsqrtf(vv.y + BN_EPS) + bb.y, 0.f);
        h.z = fmaxf(g.z * (s[q].z + bi.z - mm.z) * rsqrtf(vv.z + BN_EPS) + bb.z, 0.f);
        h.w = fmaxf(g.w * (s[q].w + bi.w - mm.w) * rsqrtf(vv.w + BN_EPS) + bb.w, 0.f);
        *(float4*)(h1s + rr * 64 + o) = h;
    }
    __syncthreads();

    const int r2 = tid >> 2;
    const int og2 = (tid & 3) << 3;
    float a2[8];
    #pragma unroll
    for (int q = 0; q < 8; ++q) a2[q] = 0.f;
    #pragma unroll 8
    for (int k = 0; k < 64; ++k) {
        float hk = h1s[r2 * 64 + k];
        float4 wa = *(const float4*)(w2 + k * 32 + og2);
        float4 wb = *(const float4*)(w2 + k * 32 + og2 + 4);
        a2[0] = fmaf(hk, wa.x, a2[0]); a2[1] = fmaf(hk, wa.y, a2[1]);
        a2[2] = fmaf(hk, wa.z, a2[2]); a2[3] = fmaf(hk, wa.w, a2[3]);
        a2[4] = fmaf(hk, wb.x, a2[4]); a2[5] = fmaf(hk, wb.y, a2[5]);
        a2[6] = fmaf(hk, wb.z, a2[6]); a2[7] = fmaf(hk, wb.w, a2[7]);
    }
    #pragma unroll
    for (int q = 0; q < 8; ++q) {
        int o = og2 + q;
        float val = g2[o] * (a2[q] + b2[o] - m2[o]) * rsqrtf(v2[o] + BN_EPS) + be2[o];
        h2s[r2 * 36 + o] = fmaxf(val, 0.f);
    }
    __syncthreads();
    if (tid < RPB) {
        float sacc = b3[0];
        #pragma unroll
        for (int k = 0; k < 32; ++k) sacc = fmaf(h2s[tid * 36 + k], w3[k], sacc);
        out[b0 + tid] = 1.0f / (1.0f + expf(-sacc));
    }
}

extern "C" void kernel_launch(void* const* d_in, const int* in_sizes, int n_in,
                              void* d_out, int out_size, void* d_ws, size_t ws_size,
                              hipStream_t stream) {
    const int*   x   = (const int*)d_in[0];
    const float* emb = (const float*)d_in[1];
    const float* sw1 = (const float*)d_in[2];
    const float* sw2 = (const float*)d_in[3];
    const float* blw = (const float*)d_in[4];
    const float* w1  = (const float*)d_in[5];
    const float* b1  = (const float*)d_in[6];
    const float* g1  = (const float*)d_in[7];
    const float* be1 = (const float*)d_in[8];
    const float* m1  = (const float*)d_in[9];
    const float* v1  = (const float*)d_in[10];
    const float* w2  = (const float*)d_in[11];
    const float* b2  = (const float*)d_in[12];
    const float* g2  = (const float*)d_in[13];
    const float* be2 = (const float*)d_in[14];
    const float* m2  = (const float*)d_in[15];
    const float* v2  = (const float*)d_in[16];
    const float* w3  = (const float*)d_in[17];
    const float* b3  = (const float*)d_in[18];
    float* out = (float*)d_out;

    // ws layout (floats): e 6,815,744 | A 425,984 | w1cat 665,600 | ypart 4,194,304
    float* ws    = (float*)d_ws;
    float* e_ws  = ws;
    float* a_ws  = ws + 6815744;
    float* w1cat = ws + 6815744 + 425984;
    float* ypart = ws + 6815744 + 425984 + 665600;   // total ~48.4 MB

    hipLaunchKernelGGL(k_w1cat, dim3(2600), dim3(256), 0, stream, w1, w1cat);
    hipLaunchKernelGGL(k_prep,  dim3(NBLK), dim3(256), 0, stream, x, emb, sw1, sw2, e_ws, a_ws);
    hipLaunchKernelGGL(k_main,  dim3(NBLK * 2), dim3(256), 0, stream, e_ws, a_ws, w1cat, blw, ypart);
    hipLaunchKernelGGL(k_epi,   dim3(NBLK), dim3(256), 0, stream, ypart,
                       b1, g1, be1, m1, v1, w2, b2, g2, be2, m2, v2, w3, b3, out);
}

// Round 5
// 174.868 us; speedup vs baseline: 3.9695x; 3.9695x over previous
//
#include <hip/hip_runtime.h>
#include <cstdint>
#include <cstddef>

// FiBiNET fused inference — MFMA bf16 version.
// B=16384, F=26, D=16, P=325 pairs, hidden 64->32->1.
// se_p = (A_i*A_j) * p  =>  y1 += u@w1a + (c*u)@w1b,  u = (e_i@W_p) .* e_j.
// Chain trick: t^T = W_p^T @ e_i^T via mfma_16x16x32_bf16 puts t in the lane
// position needed for the A-operand of the y-MFMA (m=lane&15=batch,
// k'=2d+{u,v} = quad*8+j). No per-pair LDS transpose, no per-pair barriers.
// NOTE: eS indices are in USHORT units — field f starts at f*16 (= 32 bytes).

#define F_FIELDS 26
#define P_PAIRS 325
#define BATCH 16384
#define BN_EPS 1e-3f

typedef short bf16x8 __attribute__((ext_vector_type(8)));
typedef float f32x4 __attribute__((ext_vector_type(4)));

struct PairTab { unsigned char iu[P_PAIRS]; unsigned char ju[P_PAIRS]; };
static constexpr PairTab make_pairs() {
    PairTab t{};
    int p = 0;
    for (int a = 0; a < F_FIELDS; ++a)
        for (int b = a + 1; b < F_FIELDS; ++b) { t.iu[p] = (unsigned char)a; t.ju[p] = (unsigned char)b; ++p; }
    return t;
}
__constant__ PairTab PT = make_pairs();
__constant__ int CHUNK[9] = {0, 40, 81, 121, 162, 203, 243, 284, 325};

// float -> bf16 (round to nearest even), plain bit math — no HIP class types.
__device__ __forceinline__ unsigned short bf16u(float v) {
    unsigned u = __float_as_uint(v);
    unsigned r = (u + 0x7fffu + ((u >> 16) & 1u)) >> 16;
    return (unsigned short)r;
}
__device__ __forceinline__ unsigned pk_bf16(float lo, float hi) {
    return (unsigned)bf16u(lo) | ((unsigned)bf16u(hi) << 16);
}
__device__ __forceinline__ float bflo(unsigned d) { return __uint_as_float(d << 16); }
__device__ __forceinline__ float bfhi(unsigned d) { return __uint_as_float(d & 0xffff0000u); }

// ---------------- K0: repack weights to bf16 ----------------
// w1cat [325][64 o][32 k'] bf16, k'=2d+s: s=0 -> w1[p*16+d][o], s=1 -> w1[5200+p*16+d][o]
// wcat  [325][16 dout][32 din] bf16 = W_p^T, din 16..31 zeroed (K-pad baked in)
__global__ __launch_bounds__(256) void k_wprep(const float* __restrict__ w1,
        const float* __restrict__ blw, unsigned short* __restrict__ w1cat,
        unsigned short* __restrict__ wcat) {
    int idx = blockIdx.x * 256 + threadIdx.x;
    if (idx < 325 * 64 * 32) {
        int k = idx & 31, o = (idx >> 5) & 63, p = idx >> 11;
        int d = k >> 1, su = k & 1;
        int row = su ? (5200 + p * 16 + d) : (p * 16 + d);
        w1cat[idx] = bf16u(w1[row * 64 + o]);
    } else {
        int idx2 = idx - 325 * 64 * 32;
        if (idx2 < 325 * 16 * 32) {
            int din = idx2 & 31, dout = (idx2 >> 5) & 15, p = idx2 >> 9;
            float v = (din < 16) ? blw[((size_t)p * 16 + din) * 16 + dout] : 0.f;
            wcat[idx2] = bf16u(v);
        }
    }
}

// ---------------- K1: gather embeddings (bf16 out), SE attention ----------------
__global__ __launch_bounds__(256) void k_prep(const int* __restrict__ x,
        const float* __restrict__ emb, const float* __restrict__ sw1,
        const float* __restrict__ sw2, unsigned short* __restrict__ eG,
        float* __restrict__ aG) {
    __shared__ float z_s[64][F_FIELDS];
    __shared__ float sw1_s[F_FIELDS * 13];
    __shared__ float sw2_s[13 * F_FIELDS];
    const int tid = threadIdx.x;
    const int b0 = blockIdx.x * 64;
    for (int i = tid; i < F_FIELDS * 13; i += 256) { sw1_s[i] = sw1[i]; sw2_s[i] = sw2[i]; }
    for (int idx = tid; idx < 64 * F_FIELDS; idx += 256) {
        int r = idx / F_FIELDS;
        int f = idx - r * F_FIELDS;
        int b = b0 + r;
        int id = x[b * F_FIELDS + f] + f * 1000;
        const float4* src = (const float4*)(emb + (size_t)id * 16);
        float4 v0 = src[0], v1 = src[1], v2 = src[2], v3 = src[3];
        int4 o0, o1;
        o0.x = (int)pk_bf16(v0.x, v0.y); o0.y = (int)pk_bf16(v0.z, v0.w);
        o0.z = (int)pk_bf16(v1.x, v1.y); o0.w = (int)pk_bf16(v1.z, v1.w);
        o1.x = (int)pk_bf16(v2.x, v2.y); o1.y = (int)pk_bf16(v2.z, v2.w);
        o1.z = (int)pk_bf16(v3.x, v3.y); o1.w = (int)pk_bf16(v3.z, v3.w);
        int4* dst = (int4*)(eG + ((size_t)b * F_FIELDS + f) * 16);
        dst[0] = o0; dst[1] = o1;
        float s = v0.x + v0.y + v0.z + v0.w + v1.x + v1.y + v1.z + v1.w
                + v2.x + v2.y + v2.z + v2.w + v3.x + v3.y + v3.z + v3.w;
        z_s[r][f] = s * (1.0f / 16.0f);
    }
    __syncthreads();
    if (tid < 64) {
        int b = b0 + tid;
        float s1[13];
        #pragma unroll
        for (int o = 0; o < 13; ++o) {
            float acc = 0.f;
            #pragma unroll
            for (int f = 0; f < F_FIELDS; ++f) acc = fmaf(z_s[tid][f], sw1_s[f * 13 + o], acc);
            s1[o] = fmaxf(acc, 0.0f);
        }
        #pragma unroll
        for (int f = 0; f < F_FIELDS; ++f) {
            float acc = 0.f;
            #pragma unroll
            for (int o = 0; o < 13; ++o) acc = fmaf(s1[o], sw2_s[o * F_FIELDS + f], acc);
            aG[(size_t)b * F_FIELDS + f] = fmaxf(acc, 0.0f);
        }
    }
}

// ---------------- K2: chained-MFMA bilinear + big GEMM ----------------
// grid 512 = 256 m-groups (64 rows) x 2 k-halves; 256 thr = 4 waves.
// Wave w: k-chunk s = kh*4+w, all 64 rows (4 m-tiles), all 64 outs (4 n-tiles).
// Per pair: 4x t^T-MFMA + ~13 VALU/mt (u,v build in A-layout) + 16 y-MFMA.
// No barriers in the pair loop.  eS row stride 424 ush (848B) kills bank conflicts.
__global__ __launch_bounds__(256, 2) void k_main(
        const unsigned short* __restrict__ eG, const float* __restrict__ aG,
        const unsigned short* __restrict__ w1cat, const unsigned short* __restrict__ wcat,
        unsigned short* __restrict__ ypart) {
    __shared__ __align__(16) unsigned short eS[64 * 424];
    __shared__ float aS[F_FIELDS * 64];
    const int tid = threadIdx.x;
    const int mg = blockIdx.x & 255;
    const int kh = blockIdx.x >> 8;
    const int b0 = mg * 64;

    // stage e (64 rows x 416 bf16) and A^T (26 x 64 f32)
    for (int i = tid; i < 64 * 52; i += 256) {
        int r = i / 52, seg = i - r * 52;
        int4 v = ((const int4*)(eG + (size_t)(b0 + r) * 416))[seg];
        *(int4*)(eS + r * 424 + seg * 8) = v;
    }
    for (int i = tid; i < F_FIELDS * 64; i += 256) {
        int f = i >> 6, b = i & 63;
        aS[f * 64 + b] = aG[(size_t)(b0 + b) * F_FIELDS + f];
    }
    __syncthreads();

    const int w    = tid >> 6;
    const int lane = tid & 63;
    const int ln   = lane & 15;
    const int q    = lane >> 4;
    const int s    = kh * 4 + w;
    const int p0 = CHUNK[s], p1 = CHUNK[s + 1];

    f32x4 acc[4][4];
    #pragma unroll
    for (int a = 0; a < 4; ++a)
        #pragma unroll
        for (int b = 0; b < 4; ++b) acc[a][b] = (f32x4){0.f, 0.f, 0.f, 0.f};

    const f32x4 zero4 = {0.f, 0.f, 0.f, 0.f};

    bf16x8 wa_c, wa_n;
    bf16x8 wb_c[4], wb_n[4];
    // prefetch pair p0
    wa_n = __builtin_bit_cast(bf16x8, *(const int4*)(wcat + (size_t)p0 * 512 + ln * 32 + q * 8));
    #pragma unroll
    for (int nt = 0; nt < 4; ++nt)
        wb_n[nt] = __builtin_bit_cast(bf16x8, *(const int4*)(w1cat + (size_t)p0 * 2048 + (nt * 16 + ln) * 32 + q * 8));

    bf16x8 eiB[4];
    float ai[4];
    int cur_i = -1;

    for (int p = p0; p < p1; ++p) {
        wa_c = wa_n;
        #pragma unroll
        for (int nt = 0; nt < 4; ++nt) wb_c[nt] = wb_n[nt];
        if (p + 1 < p1) {
            wa_n = __builtin_bit_cast(bf16x8, *(const int4*)(wcat + (size_t)(p + 1) * 512 + ln * 32 + q * 8));
            #pragma unroll
            for (int nt = 0; nt < 4; ++nt)
                wb_n[nt] = __builtin_bit_cast(bf16x8, *(const int4*)(w1cat + (size_t)(p + 1) * 2048 + (nt * 16 + ln) * 32 + q * 8));
        }
        const int iu = PT.iu[p], ju = PT.ju[p];
        if (iu != cur_i) {
            cur_i = iu;
            #pragma unroll
            for (int mt = 0; mt < 4; ++mt) {
                eiB[mt] = __builtin_bit_cast(bf16x8,
                    *(const int4*)(eS + (mt * 16 + ln) * 424 + iu * 16 + (q & 1) * 8));
                ai[mt] = aS[iu * 64 + mt * 16 + ln];
            }
        }
        #pragma unroll
        for (int mt = 0; mt < 4; ++mt) {
            // t^T tile: lane holds t[b=16mt+ln][d=4q+r], r=0..3
            f32x4 t = __builtin_amdgcn_mfma_f32_16x16x32_bf16(wa_c, eiB[mt], zero4, 0, 0, 0);
            uint2 ej = *(const uint2*)(eS + (mt * 16 + ln) * 424 + ju * 16 + q * 4);
            float e0 = bflo(ej.x), e1 = bfhi(ej.x), e2 = bflo(ej.y), e3 = bfhi(ej.y);
            float aj = aS[ju * 64 + mt * 16 + ln];
            float c  = ai[mt] * aj;
            float u0 = t[0] * e0, u1 = t[1] * e1, u2 = t[2] * e2, u3 = t[3] * e3;
            int4 af;
            af.x = (int)pk_bf16(u0, c * u0);
            af.y = (int)pk_bf16(u1, c * u1);
            af.z = (int)pk_bf16(u2, c * u2);
            af.w = (int)pk_bf16(u3, c * u3);
            bf16x8 A = __builtin_bit_cast(bf16x8, af);
            #pragma unroll
            for (int nt = 0; nt < 4; ++nt)
                acc[mt][nt] = __builtin_amdgcn_mfma_f32_16x16x32_bf16(A, wb_c[nt], acc[mt][nt], 0, 0, 0);
        }
    }

    unsigned short* yp = ypart + ((size_t)s * BATCH + b0) * 64;
    #pragma unroll
    for (int mt = 0; mt < 4; ++mt)
        #pragma unroll
        for (int nt = 0; nt < 4; ++nt)
            #pragma unroll
            for (int r = 0; r < 4; ++r)
                yp[(mt * 16 + q * 4 + r) * 64 + nt * 16 + ln] = bf16u(acc[mt][nt][r]);
}

// ---------------- K3: merge 8 bf16 partials + BN/ReLU MLP tail ----------------
__global__ __launch_bounds__(256) void k_epi(
        const unsigned short* __restrict__ ypart,
        const float* __restrict__ b1, const float* __restrict__ g1,
        const float* __restrict__ be1, const float* __restrict__ m1,
        const float* __restrict__ v1,
        const float* __restrict__ w2, const float* __restrict__ b2,
        const float* __restrict__ g2, const float* __restrict__ be2,
        const float* __restrict__ m2, const float* __restrict__ v2,
        const float* __restrict__ w3, const float* __restrict__ b3,
        float* __restrict__ out) {
    __shared__ __align__(16) float h1s[64 * 64];
    __shared__ float h2s[64 * 36];
    const int tid = threadIdx.x;
    const int b0 = blockIdx.x * 64;
    const int rr = tid >> 2;
    const int cc = (tid & 3) << 4;

    float s[16];
    #pragma unroll
    for (int i = 0; i < 16; ++i) s[i] = 0.f;
    for (int part = 0; part < 8; ++part) {
        const unsigned short* src = ypart + ((size_t)part * BATCH + b0 + rr) * 64 + cc;
        int4 A = ((const int4*)src)[0];
        int4 Bv = ((const int4*)src)[1];
        s[0] += bflo(A.x);  s[1] += bfhi(A.x);  s[2] += bflo(A.y);  s[3] += bfhi(A.y);
        s[4] += bflo(A.z);  s[5] += bfhi(A.z);  s[6] += bflo(A.w);  s[7] += bfhi(A.w);
        s[8] += bflo(Bv.x); s[9] += bfhi(Bv.x); s[10] += bflo(Bv.y); s[11] += bfhi(Bv.y);
        s[12] += bflo(Bv.z); s[13] += bfhi(Bv.z); s[14] += bflo(Bv.w); s[15] += bfhi(Bv.w);
    }
    #pragma unroll
    for (int g = 0; g < 4; ++g) {
        int o = cc + g * 4;
        float4 gg = *(const float4*)(g1 + o);
        float4 vv = *(const float4*)(v1 + o);
        float4 mm = *(const float4*)(m1 + o);
        float4 bb = *(const float4*)(be1 + o);
        float4 bi = *(const float4*)(b1 + o);
        float4 h;
        h.x = fmaxf(gg.x * (s[g*4+0] + bi.x - mm.x) * rsqrtf(vv.x + BN_EPS) + bb.x, 0.f);
        h.y = fmaxf(gg.y * (s[g*4+1] + bi.y - mm.y) * rsqrtf(vv.y + BN_EPS) + bb.y, 0.f);
        h.z = fmaxf(gg.z * (s[g*4+2] + bi.z - mm.z) * rsqrtf(vv.z + BN_EPS) + bb.z, 0.f);
        h.w = fmaxf(gg.w * (s[g*4+3] + bi.w - mm.w) * rsqrtf(vv.w + BN_EPS) + bb.w, 0.f);
        *(float4*)(h1s + rr * 64 + o) = h;
    }
    __syncthreads();

    const int r2 = tid >> 2;
    const int og2 = (tid & 3) << 3;
    float a2[8];
    #pragma unroll
    for (int qq = 0; qq < 8; ++qq) a2[qq] = 0.f;
    #pragma unroll 8
    for (int k = 0; k < 64; ++k) {
        float hk = h1s[r2 * 64 + k];
        float4 wa = *(const float4*)(w2 + k * 32 + og2);
        float4 wb = *(const float4*)(w2 + k * 32 + og2 + 4);
        a2[0] = fmaf(hk, wa.x, a2[0]); a2[1] = fmaf(hk, wa.y, a2[1]);
        a2[2] = fmaf(hk, wa.z, a2[2]); a2[3] = fmaf(hk, wa.w, a2[3]);
        a2[4] = fmaf(hk, wb.x, a2[4]); a2[5] = fmaf(hk, wb.y, a2[5]);
        a2[6] = fmaf(hk, wb.z, a2[6]); a2[7] = fmaf(hk, wb.w, a2[7]);
    }
    #pragma unroll
    for (int qq = 0; qq < 8; ++qq) {
        int o = og2 + qq;
        float val = g2[o] * (a2[qq] + b2[o] - m2[o]) * rsqrtf(v2[o] + BN_EPS) + be2[o];
        h2s[r2 * 36 + o] = fmaxf(val, 0.f);
    }
    __syncthreads();
    if (tid < 64) {
        float sacc = b3[0];
        #pragma unroll
        for (int k = 0; k < 32; ++k) sacc = fmaf(h2s[tid * 36 + k], w3[k], sacc);
        out[b0 + tid] = 1.0f / (1.0f + expf(-sacc));
    }
}

extern "C" void kernel_launch(void* const* d_in, const int* in_sizes, int n_in,
                              void* d_out, int out_size, void* d_ws, size_t ws_size,
                              hipStream_t stream) {
    const int*   x   = (const int*)d_in[0];
    const float* emb = (const float*)d_in[1];
    const float* sw1 = (const float*)d_in[2];
    const float* sw2 = (const float*)d_in[3];
    const float* blw = (const float*)d_in[4];
    const float* w1  = (const float*)d_in[5];
    const float* b1  = (const float*)d_in[6];
    const float* g1  = (const float*)d_in[7];
    const float* be1 = (const float*)d_in[8];
    const float* m1  = (const float*)d_in[9];
    const float* v1  = (const float*)d_in[10];
    const float* w2  = (const float*)d_in[11];
    const float* b2  = (const float*)d_in[12];
    const float* g2  = (const float*)d_in[13];
    const float* be2 = (const float*)d_in[14];
    const float* m2  = (const float*)d_in[15];
    const float* v2  = (const float*)d_in[16];
    const float* w3  = (const float*)d_in[17];
    const float* b3  = (const float*)d_in[18];
    float* out = (float*)d_out;

    // ws layout (bytes, all 16B-aligned):
    // eG bf16 13,631,488 | aG f32 1,703,936 | w1cat bf16 1,331,200 |
    // wcat bf16 332,800 | ypart bf16 16,777,216  -> total 33.8 MB
    char* ws = (char*)d_ws;
    unsigned short* eG    = (unsigned short*)ws;
    float*          aG    = (float*)(ws + 13631488);
    unsigned short* w1cat = (unsigned short*)(ws + 15335424);
    unsigned short* wcat  = (unsigned short*)(ws + 16666624);
    unsigned short* ypart = (unsigned short*)(ws + 16999424);

    hipLaunchKernelGGL(k_wprep, dim3(3250), dim3(256), 0, stream, w1, blw, w1cat, wcat);
    hipLaunchKernelGGL(k_prep,  dim3(256),  dim3(256), 0, stream, x, emb, sw1, sw2, eG, aG);
    hipLaunchKernelGGL(k_main,  dim3(512),  dim3(256), 0, stream, eG, aG, w1cat, wcat, ypart);
    hipLaunchKernelGGL(k_epi,   dim3(256),  dim3(256), 0, stream, ypart,
                       b1, g1, be1, m1, v1, w2, b2, g2, be2, m2, v2, w3, b3, out);
}

// Round 6
// 172.534 us; speedup vs baseline: 4.0232x; 1.0135x over previous
//
#include <hip/hip_runtime.h>
#include <cstdint>
#include <cstddef>

// FiBiNET fused inference — MFMA bf16, chained-layout, perm-packed A-frags.
// B=16384, F=26, D=16, P=325 pairs, hidden 64->32->1.
// se_p = (A_i*A_j) * p  =>  y1 += u@w1a + (c*u)@w1b,  u = (e_i@W_p) .* e_j.
// t^T = W_p^T @ e_i^T (16x16x32, K zero-padded in wcat) lands each lane at
// the A-operand slot of the y-MFMA (m=lane&15=batch, k'=2d+{u,cu}=q*8+j).
// A-frag built with v_perm truncating packs (1 op per bf16 pair).
// eS indices in USHORT units: field f at f*16 (32 B). Row stride 424 ush.

#define F_FIELDS 26
#define P_PAIRS 325
#define BATCH 16384
#define BN_EPS 1e-3f

typedef short bf16x8 __attribute__((ext_vector_type(8)));
typedef float f32x4 __attribute__((ext_vector_type(4)));

struct PairTab { unsigned char iu[P_PAIRS]; unsigned char ju[P_PAIRS]; };
static constexpr PairTab make_pairs() {
    PairTab t{};
    int p = 0;
    for (int a = 0; a < F_FIELDS; ++a)
        for (int b = a + 1; b < F_FIELDS; ++b) { t.iu[p] = (unsigned char)a; t.ju[p] = (unsigned char)b; ++p; }
    return t;
}
__constant__ PairTab PT = make_pairs();
__constant__ int CHUNK[9] = {0, 40, 81, 121, 162, 203, 243, 284, 325};

// float -> bf16 RNE (used off the hot path)
__device__ __forceinline__ unsigned short bf16u(float v) {
    unsigned u = __float_as_uint(v);
    unsigned r = (u + 0x7fffu + ((u >> 16) & 1u)) >> 16;
    return (unsigned short)r;
}
__device__ __forceinline__ unsigned pk_bf16(float lo, float hi) {
    return (unsigned)bf16u(lo) | ((unsigned)bf16u(hi) << 16);
}
__device__ __forceinline__ float bflo(unsigned d) { return __uint_as_float(d << 16); }
__device__ __forceinline__ float bfhi(unsigned d) { return __uint_as_float(d & 0xffff0000u); }
// truncating pack: dst = (hi16(cu) << 16) | hi16(u)  — one v_perm_b32
__device__ __forceinline__ unsigned pk_trunc(float u, float cu) {
    return __builtin_amdgcn_perm(__float_as_uint(cu), __float_as_uint(u), 0x07060302u);
}

// ---------------- K1: merged prep ----------------
// blocks 0..255: gather embeddings (bf16) + SE attention.
// blocks 256..3505: repack w1 -> w1cat [325][64 o][32 k'] and blw -> wcat
//                   [325][16 dout][32 din] (din 16..31 zeroed).
__global__ __launch_bounds__(256) void k_prep(const int* __restrict__ x,
        const float* __restrict__ emb, const float* __restrict__ sw1,
        const float* __restrict__ sw2, const float* __restrict__ w1,
        const float* __restrict__ blw, unsigned short* __restrict__ eG,
        float* __restrict__ aG, unsigned short* __restrict__ w1cat,
        unsigned short* __restrict__ wcat) {
    const int tid = threadIdx.x;
    if (blockIdx.x >= 256) {
        int idx = (blockIdx.x - 256) * 256 + tid;
        if (idx < 325 * 64 * 32) {
            int k = idx & 31, o = (idx >> 5) & 63, p = idx >> 11;
            int d = k >> 1, su = k & 1;
            int row = su ? (5200 + p * 16 + d) : (p * 16 + d);
            w1cat[idx] = bf16u(w1[row * 64 + o]);
        } else {
            int idx2 = idx - 325 * 64 * 32;
            if (idx2 < 325 * 16 * 32) {
                int din = idx2 & 31, dout = (idx2 >> 5) & 15, p = idx2 >> 9;
                float v = (din < 16) ? blw[((size_t)p * 16 + din) * 16 + dout] : 0.f;
                wcat[idx2] = bf16u(v);
            }
        }
        return;
    }
    __shared__ float z_s[64][F_FIELDS];
    __shared__ float sw1_s[F_FIELDS * 13];
    __shared__ float sw2_s[13 * F_FIELDS];
    const int b0 = blockIdx.x * 64;
    for (int i = tid; i < F_FIELDS * 13; i += 256) { sw1_s[i] = sw1[i]; sw2_s[i] = sw2[i]; }
    for (int idx = tid; idx < 64 * F_FIELDS; idx += 256) {
        int r = idx / F_FIELDS;
        int f = idx - r * F_FIELDS;
        int b = b0 + r;
        int id = x[b * F_FIELDS + f] + f * 1000;
        const float4* src = (const float4*)(emb + (size_t)id * 16);
        float4 v0 = src[0], v1 = src[1], v2 = src[2], v3 = src[3];
        int4 o0, o1;
        o0.x = (int)pk_bf16(v0.x, v0.y); o0.y = (int)pk_bf16(v0.z, v0.w);
        o0.z = (int)pk_bf16(v1.x, v1.y); o0.w = (int)pk_bf16(v1.z, v1.w);
        o1.x = (int)pk_bf16(v2.x, v2.y); o1.y = (int)pk_bf16(v2.z, v2.w);
        o1.z = (int)pk_bf16(v3.x, v3.y); o1.w = (int)pk_bf16(v3.z, v3.w);
        int4* dst = (int4*)(eG + ((size_t)b * F_FIELDS + f) * 16);
        dst[0] = o0; dst[1] = o1;
        float s = v0.x + v0.y + v0.z + v0.w + v1.x + v1.y + v1.z + v1.w
                + v2.x + v2.y + v2.z + v2.w + v3.x + v3.y + v3.z + v3.w;
        z_s[r][f] = s * (1.0f / 16.0f);
    }
    __syncthreads();
    if (tid < 64) {
        int b = b0 + tid;
        float s1[13];
        #pragma unroll
        for (int o = 0; o < 13; ++o) {
            float acc = 0.f;
            #pragma unroll
            for (int f = 0; f < F_FIELDS; ++f) acc = fmaf(z_s[tid][f], sw1_s[f * 13 + o], acc);
            s1[o] = fmaxf(acc, 0.0f);
        }
        #pragma unroll
        for (int f = 0; f < F_FIELDS; ++f) {
            float acc = 0.f;
            #pragma unroll
            for (int o = 0; o < 13; ++o) acc = fmaf(s1[o], sw2_s[o * F_FIELDS + f], acc);
            aG[(size_t)b * F_FIELDS + f] = fmaxf(acc, 0.0f);
        }
    }
}

// ---------------- K2: chained-MFMA bilinear + big GEMM ----------------
// grid 256 blocks x 512 thr (8 waves). Block owns 64 batch rows; wave w owns
// pair chunk w (CHUNK). Per pair: 4x t-MFMA (pipelined 1 ahead) + perm-packed
// A-build + 16 y-MFMA. Weights prefetched 1 pair ahead. No barriers in loop.
__global__ __launch_bounds__(512, 2) void k_main(
        const unsigned short* __restrict__ eG, const float* __restrict__ aG,
        const unsigned short* __restrict__ w1cat, const unsigned short* __restrict__ wcat,
        unsigned short* __restrict__ ypart) {
    __shared__ __align__(16) unsigned short eS[64 * 424];
    __shared__ float aS[F_FIELDS * 64];
    const int tid = threadIdx.x;
    const int b0 = blockIdx.x * 64;

    for (int i = tid; i < 64 * 52; i += 512) {
        int r = i / 52, seg = i - r * 52;
        int4 v = ((const int4*)(eG + (size_t)(b0 + r) * 416))[seg];
        *(int4*)(eS + r * 424 + seg * 8) = v;
    }
    for (int i = tid; i < F_FIELDS * 64; i += 512) {
        int f = i >> 6, b = i & 63;
        aS[f * 64 + b] = aG[(size_t)(b0 + b) * F_FIELDS + f];
    }
    __syncthreads();

    const int w    = tid >> 6;      // wave = chunk id
    const int lane = tid & 63;
    const int ln   = lane & 15;
    const int q    = lane >> 4;
    const int p0 = CHUNK[w], p1 = CHUNK[w + 1];

    f32x4 acc[4][4];
    #pragma unroll
    for (int a = 0; a < 4; ++a)
        #pragma unroll
        for (int b = 0; b < 4; ++b) acc[a][b] = (f32x4){0.f, 0.f, 0.f, 0.f};
    const f32x4 zero4 = {0.f, 0.f, 0.f, 0.f};

    // prologue: weights + e_i frags + t for p0
    int iu_c = PT.iu[p0];
    bf16x8 eiB[4];
    float ai[4];
    #pragma unroll
    for (int mt = 0; mt < 4; ++mt) {
        eiB[mt] = __builtin_bit_cast(bf16x8,
            *(const int4*)(eS + (mt * 16 + ln) * 424 + iu_c * 16 + (q & 1) * 8));
        ai[mt] = aS[iu_c * 64 + mt * 16 + ln];
    }
    bf16x8 wa_c = __builtin_bit_cast(bf16x8, *(const int4*)(wcat + (size_t)p0 * 512 + ln * 32 + q * 8));
    bf16x8 wb_c[4];
    #pragma unroll
    for (int nt = 0; nt < 4; ++nt)
        wb_c[nt] = __builtin_bit_cast(bf16x8, *(const int4*)(w1cat + (size_t)p0 * 2048 + (nt * 16 + ln) * 32 + q * 8));
    f32x4 tc[4];
    #pragma unroll
    for (int mt = 0; mt < 4; ++mt)
        tc[mt] = __builtin_amdgcn_mfma_f32_16x16x32_bf16(wa_c, eiB[mt], zero4, 0, 0, 0);

    for (int p = p0; p < p1; ++p) {
        const bool more = (p + 1 < p1);
        bf16x8 wa_n, wb_n[4];
        if (more) {
            wa_n = __builtin_bit_cast(bf16x8, *(const int4*)(wcat + (size_t)(p + 1) * 512 + ln * 32 + q * 8));
            #pragma unroll
            for (int nt = 0; nt < 4; ++nt)
                wb_n[nt] = __builtin_bit_cast(bf16x8, *(const int4*)(w1cat + (size_t)(p + 1) * 2048 + (nt * 16 + ln) * 32 + q * 8));
        }
        const int ju = PT.ju[p];
        uint2 ejv[4];
        float cv[4];
        #pragma unroll
        for (int mt = 0; mt < 4; ++mt) {
            ejv[mt] = *(const uint2*)(eS + (mt * 16 + ln) * 424 + ju * 16 + q * 4);
            cv[mt]  = ai[mt] * aS[ju * 64 + mt * 16 + ln];
        }
        // issue t for p+1 before consuming tc (software pipeline)
        f32x4 tn[4];
        if (more) {
            const int iu_n = PT.iu[p + 1];
            if (iu_n != iu_c) {
                iu_c = iu_n;
                #pragma unroll
                for (int mt = 0; mt < 4; ++mt) {
                    eiB[mt] = __builtin_bit_cast(bf16x8,
                        *(const int4*)(eS + (mt * 16 + ln) * 424 + iu_c * 16 + (q & 1) * 8));
                    ai[mt] = aS[iu_c * 64 + mt * 16 + ln];
                }
            }
            #pragma unroll
            for (int mt = 0; mt < 4; ++mt)
                tn[mt] = __builtin_amdgcn_mfma_f32_16x16x32_bf16(wa_n, eiB[mt], zero4, 0, 0, 0);
        }
        #pragma unroll
        for (int mt = 0; mt < 4; ++mt) {
            float e0 = bflo(ejv[mt].x), e1 = bfhi(ejv[mt].x);
            float e2 = bflo(ejv[mt].y), e3 = bfhi(ejv[mt].y);
            float c  = cv[mt];
            float u0 = tc[mt][0] * e0, u1 = tc[mt][1] * e1;
            float u2 = tc[mt][2] * e2, u3 = tc[mt][3] * e3;
            int4 af;
            af.x = (int)pk_trunc(u0, c * u0);
            af.y = (int)pk_trunc(u1, c * u1);
            af.z = (int)pk_trunc(u2, c * u2);
            af.w = (int)pk_trunc(u3, c * u3);
            bf16x8 A = __builtin_bit_cast(bf16x8, af);
            #pragma unroll
            for (int nt = 0; nt < 4; ++nt)
                acc[mt][nt] = __builtin_amdgcn_mfma_f32_16x16x32_bf16(A, wb_c[nt], acc[mt][nt], 0, 0, 0);
        }
        if (more) {
            #pragma unroll
            for (int mt = 0; mt < 4; ++mt) tc[mt] = tn[mt];
            wa_c = wa_n;
            #pragma unroll
            for (int nt = 0; nt < 4; ++nt) wb_c[nt] = wb_n[nt];
        }
    }

    unsigned short* yp = ypart + ((size_t)w * BATCH + b0) * 64;
    #pragma unroll
    for (int mt = 0; mt < 4; ++mt)
        #pragma unroll
        for (int nt = 0; nt < 4; ++nt)
            #pragma unroll
            for (int r = 0; r < 4; ++r)
                yp[(mt * 16 + q * 4 + r) * 64 + nt * 16 + ln] = bf16u(acc[mt][nt][r]);
}

// ---------------- K3: merge 8 bf16 partials + BN/ReLU MLP tail ----------------
__global__ __launch_bounds__(256) void k_epi(
        const unsigned short* __restrict__ ypart,
        const float* __restrict__ b1, const float* __restrict__ g1,
        const float* __restrict__ be1, const float* __restrict__ m1,
        const float* __restrict__ v1,
        const float* __restrict__ w2, const float* __restrict__ b2,
        const float* __restrict__ g2, const float* __restrict__ be2,
        const float* __restrict__ m2, const float* __restrict__ v2,
        const float* __restrict__ w3, const float* __restrict__ b3,
        float* __restrict__ out) {
    __shared__ __align__(16) float h1s[64 * 64];
    __shared__ float h2s[64 * 36];
    const int tid = threadIdx.x;
    const int b0 = blockIdx.x * 64;
    const int rr = tid >> 2;
    const int cc = (tid & 3) << 4;

    float s[16];
    #pragma unroll
    for (int i = 0; i < 16; ++i) s[i] = 0.f;
    for (int part = 0; part < 8; ++part) {
        const unsigned short* src = ypart + ((size_t)part * BATCH + b0 + rr) * 64 + cc;
        int4 A = ((const int4*)src)[0];
        int4 Bv = ((const int4*)src)[1];
        s[0] += bflo(A.x);  s[1] += bfhi(A.x);  s[2] += bflo(A.y);  s[3] += bfhi(A.y);
        s[4] += bflo(A.z);  s[5] += bfhi(A.z);  s[6] += bflo(A.w);  s[7] += bfhi(A.w);
        s[8] += bflo(Bv.x); s[9] += bfhi(Bv.x); s[10] += bflo(Bv.y); s[11] += bfhi(Bv.y);
        s[12] += bflo(Bv.z); s[13] += bfhi(Bv.z); s[14] += bflo(Bv.w); s[15] += bfhi(Bv.w);
    }
    #pragma unroll
    for (int g = 0; g < 4; ++g) {
        int o = cc + g * 4;
        float4 gg = *(const float4*)(g1 + o);
        float4 vv = *(const float4*)(v1 + o);
        float4 mm = *(const float4*)(m1 + o);
        float4 bb = *(const float4*)(be1 + o);
        float4 bi = *(const float4*)(b1 + o);
        float4 h;
        h.x = fmaxf(gg.x * (s[g*4+0] + bi.x - mm.x) * rsqrtf(vv.x + BN_EPS) + bb.x, 0.f);
        h.y = fmaxf(gg.y * (s[g*4+1] + bi.y - mm.y) * rsqrtf(vv.y + BN_EPS) + bb.y, 0.f);
        h.z = fmaxf(gg.z * (s[g*4+2] + bi.z - mm.z) * rsqrtf(vv.z + BN_EPS) + bb.z, 0.f);
        h.w = fmaxf(gg.w * (s[g*4+3] + bi.w - mm.w) * rsqrtf(vv.w + BN_EPS) + bb.w, 0.f);
        *(float4*)(h1s + rr * 64 + o) = h;
    }
    __syncthreads();

    const int r2 = tid >> 2;
    const int og2 = (tid & 3) << 3;
    float a2[8];
    #pragma unroll
    for (int qq = 0; qq < 8; ++qq) a2[qq] = 0.f;
    #pragma unroll 8
    for (int k = 0; k < 64; ++k) {
        float hk = h1s[r2 * 64 + k];
        float4 wa = *(const float4*)(w2 + k * 32 + og2);
        float4 wb = *(const float4*)(w2 + k * 32 + og2 + 4);
        a2[0] = fmaf(hk, wa.x, a2[0]); a2[1] = fmaf(hk, wa.y, a2[1]);
        a2[2] = fmaf(hk, wa.z, a2[2]); a2[3] = fmaf(hk, wa.w, a2[3]);
        a2[4] = fmaf(hk, wb.x, a2[4]); a2[5] = fmaf(hk, wb.y, a2[5]);
        a2[6] = fmaf(hk, wb.z, a2[6]); a2[7] = fmaf(hk, wb.w, a2[7]);
    }
    #pragma unroll
    for (int qq = 0; qq < 8; ++qq) {
        int o = og2 + qq;
        float val = g2[o] * (a2[qq] + b2[o] - m2[o]) * rsqrtf(v2[o] + BN_EPS) + be2[o];
        h2s[r2 * 36 + o] = fmaxf(val, 0.f);
    }
    __syncthreads();
    if (tid < 64) {
        float sacc = b3[0];
        #pragma unroll
        for (int k = 0; k < 32; ++k) sacc = fmaf(h2s[tid * 36 + k], w3[k], sacc);
        out[b0 + tid] = 1.0f / (1.0f + expf(-sacc));
    }
}

extern "C" void kernel_launch(void* const* d_in, const int* in_sizes, int n_in,
                              void* d_out, int out_size, void* d_ws, size_t ws_size,
                              hipStream_t stream) {
    const int*   x   = (const int*)d_in[0];
    const float* emb = (const float*)d_in[1];
    const float* sw1 = (const float*)d_in[2];
    const float* sw2 = (const float*)d_in[3];
    const float* blw = (const float*)d_in[4];
    const float* w1  = (const float*)d_in[5];
    const float* b1  = (const float*)d_in[6];
    const float* g1  = (const float*)d_in[7];
    const float* be1 = (const float*)d_in[8];
    const float* m1  = (const float*)d_in[9];
    const float* v1  = (const float*)d_in[10];
    const float* w2  = (const float*)d_in[11];
    const float* b2  = (const float*)d_in[12];
    const float* g2  = (const float*)d_in[13];
    const float* be2 = (const float*)d_in[14];
    const float* m2  = (const float*)d_in[15];
    const float* v2  = (const float*)d_in[16];
    const float* w3  = (const float*)d_in[17];
    const float* b3  = (const float*)d_in[18];
    float* out = (float*)d_out;

    // ws layout (bytes): eG 13,631,488 | aG 1,703,936 | w1cat 1,331,200 |
    // wcat 332,800 | ypart 16,777,216  -> ~33.8 MB
    char* ws = (char*)d_ws;
    unsigned short* eG    = (unsigned short*)ws;
    float*          aG    = (float*)(ws + 13631488);
    unsigned short* w1cat = (unsigned short*)(ws + 15335424);
    unsigned short* wcat  = (unsigned short*)(ws + 16666624);
    unsigned short* ypart = (unsigned short*)(ws + 16999424);

    hipLaunchKernelGGL(k_prep, dim3(3506), dim3(256), 0, stream,
                       x, emb, sw1, sw2, w1, blw, eG, aG, w1cat, wcat);
    hipLaunchKernelGGL(k_main, dim3(256), dim3(512), 0, stream, eG, aG, w1cat, wcat, ypart);
    hipLaunchKernelGGL(k_epi,  dim3(256), dim3(256), 0, stream, ypart,
                       b1, g1, be1, m1, v1, w2, b2, g2, be2, m2, v2, w3, b3, out);
}